// Round 3
// baseline (7494.486 us; speedup 1.0000x reference)
//
#include <hip/hip_runtime.h>
#include <hip/hip_bf16.h>
#include <math.h>

typedef __hip_bfloat16 bf16;
typedef __attribute__((ext_vector_type(8))) short bf16x8;
typedef __attribute__((ext_vector_type(4))) float f32x4;

#define DEPTH  4
#define HEADS  16
#define DIM    1024
#define DHEAD  64
#define MLPD   4096
#define BB     4
#define NN     1024
#define MMK    1024
#define ROWS   (BB*NN)     // 4096 token rows

// ---------------- f32 -> bf16 convert ----------------
__global__ __launch_bounds__(256) void f2b_kernel(const float* __restrict__ in, bf16* __restrict__ out, int n) {
  int i = blockIdx.x * 256 + threadIdx.x;
  if (i < n) out[i] = __float2bfloat16(in[i]);
}

// ---------------- generalized transpose + f32->bf16 ----------------
// out[n][k] = bf16( in[(rowOff + k) * inStride + colOff + n] )
// grid: (Ncols/32, Krows/32), block (32,8).
__global__ __launch_bounds__(256) void transpose_f2b(const float* __restrict__ in, bf16* __restrict__ out,
                                                     int inStride, int rowOff, int colOff, int outStride) {
  __shared__ float tile[32][33];
  int n0 = blockIdx.x * 32, k0 = blockIdx.y * 32;
  int tx = threadIdx.x, ty = threadIdx.y;          // 32 x 8
  #pragma unroll
  for (int i = 0; i < 32; i += 8)
    tile[ty + i][tx] = in[(size_t)(rowOff + k0 + ty + i) * inStride + colOff + n0 + tx];
  __syncthreads();
  #pragma unroll
  for (int i = 0; i < 32; i += 8)
    out[(size_t)(n0 + ty + i) * outStride + k0 + tx] = __float2bfloat16(tile[tx][ty + i]);
}

// ---------------- layernorm: f32 in -> bf16 out (w,b are f32) ----------------
__global__ __launch_bounds__(256) void ln_kernel(const float* __restrict__ x, const float* __restrict__ w,
                                                 const float* __restrict__ b, bf16* __restrict__ out) {
  int row = blockIdx.x, t = threadIdx.x;
  const float* xr = x + (size_t)row * DIM;
  float4 xv = *(const float4*)(xr + t * 4);
  float s  = xv.x + xv.y + xv.z + xv.w;
  float s2 = xv.x * xv.x + xv.y * xv.y + xv.z * xv.z + xv.w * xv.w;
  #pragma unroll
  for (int off = 32; off; off >>= 1) { s += __shfl_xor(s, off, 64); s2 += __shfl_xor(s2, off, 64); }
  __shared__ float sh_s[4], sh_s2[4], sh_mu, sh_rstd;
  int wid = t >> 6;
  if ((t & 63) == 0) { sh_s[wid] = s; sh_s2[wid] = s2; }
  __syncthreads();
  if (t == 0) {
    float S1 = sh_s[0] + sh_s[1] + sh_s[2] + sh_s[3];
    float S2 = sh_s2[0] + sh_s2[1] + sh_s2[2] + sh_s2[3];
    float mu = S1 * (1.0f / DIM);
    float var = S2 * (1.0f / DIM) - mu * mu;
    sh_mu = mu; sh_rstd = rsqrtf(var + 1e-5f);
  }
  __syncthreads();
  float mu = sh_mu, rstd = sh_rstd;
  float4 wv = *(const float4*)(w + t * 4);
  float4 bv = *(const float4*)(b + t * 4);
  bf16* orow = out + (size_t)row * DIM + t * 4;
  orow[0] = __float2bfloat16((xv.x - mu) * rstd * wv.x + bv.x);
  orow[1] = __float2bfloat16((xv.y - mu) * rstd * wv.y + bv.y);
  orow[2] = __float2bfloat16((xv.z - mu) * rstd * wv.z + bv.z);
  orow[3] = __float2bfloat16((xv.w - mu) * rstd * wv.w + bv.w);
}

// ---------------- GEMM: C = A(M,K) x Bt(N,K)^T ----------------
// mode 0: store bf16 C
// mode 1: C += bias; gelu(exact); store bf16
// mode 2: resf += C (+ bias if bias != nullptr)  (fp32 read-modify-write residual)
#define MODE_PLAIN 0
#define MODE_GELU  1
#define MODE_RES   2
#define LDK 40   // padded LDS row (32 + 8 bf16 -> 80B rows, 16B aligned)

__global__ __launch_bounds__(256) void gemm_kernel(const bf16* __restrict__ A, const bf16* __restrict__ Bt,
                                                   const float* __restrict__ bias, bf16* __restrict__ outb,
                                                   float* __restrict__ resf, int N, int K, int mode) {
  __shared__ bf16 As[64][LDK];
  __shared__ bf16 Bs[64][LDK];
  int t = threadIdx.x;
  int col0 = blockIdx.x * 64, row0 = blockIdx.y * 64;
  int lane = t & 63, wid = t >> 6;
  int wm = (wid >> 1) * 32, wn = (wid & 1) * 32;
  int l15 = lane & 15, quad = lane >> 4;
  int am = t >> 2, ak = (t & 3) * 8;   // staging coords (also Bt rows)

  f32x4 acc00 = {}, acc01 = {}, acc10 = {}, acc11 = {};

  const bf16* aptr = A  + (size_t)(row0 + am) * K + ak;
  const bf16* bptr = Bt + (size_t)(col0 + am) * K + ak;

  for (int k0 = 0; k0 < K; k0 += 32) {
    *(bf16x8*)(&As[am][ak]) = *(const bf16x8*)(aptr + k0);
    *(bf16x8*)(&Bs[am][ak]) = *(const bf16x8*)(bptr + k0);
    __syncthreads();
    bf16x8 a0 = *(const bf16x8*)(&As[wm + l15][quad * 8]);
    bf16x8 a1 = *(const bf16x8*)(&As[wm + 16 + l15][quad * 8]);
    bf16x8 b0 = *(const bf16x8*)(&Bs[wn + l15][quad * 8]);
    bf16x8 b1 = *(const bf16x8*)(&Bs[wn + 16 + l15][quad * 8]);
    acc00 = __builtin_amdgcn_mfma_f32_16x16x32_bf16(a0, b0, acc00, 0, 0, 0);
    acc01 = __builtin_amdgcn_mfma_f32_16x16x32_bf16(a0, b1, acc01, 0, 0, 0);
    acc10 = __builtin_amdgcn_mfma_f32_16x16x32_bf16(a1, b0, acc10, 0, 0, 0);
    acc11 = __builtin_amdgcn_mfma_f32_16x16x32_bf16(a1, b1, acc11, 0, 0, 0);
    __syncthreads();
  }

  // epilogue: row = row0+wm+i*16+quad*4+r, col = col0+wn+j*16+l15
  f32x4 accs[2][2] = {{acc00, acc01}, {acc10, acc11}};
  #pragma unroll
  for (int i = 0; i < 2; ++i) {
    #pragma unroll
    for (int j = 0; j < 2; ++j) {
      int gcol = col0 + wn + j * 16 + l15;
      float bval = (mode != MODE_PLAIN && bias != nullptr) ? bias[gcol] : 0.0f;
      #pragma unroll
      for (int r = 0; r < 4; ++r) {
        int grow = row0 + wm + i * 16 + quad * 4 + r;
        float val = accs[i][j][r];
        size_t idx = (size_t)grow * N + gcol;
        if (mode == MODE_RES) {
          resf[idx] = resf[idx] + val + bval;
        } else {
          if (mode == MODE_GELU) {
            float u = val + bval;
            val = 0.5f * u * (1.0f + erff(u * 0.70710678118654752f));
          }
          outb[idx] = __float2bfloat16(val);
        }
      }
    }
  }
}

// ---------------- attention: 8 query rows per block, one (b,head) ----------------
__global__ __launch_bounds__(256) void attn_kernel(const bf16* __restrict__ q, const bf16* __restrict__ k,
                                                   const bf16* __restrict__ v, bf16* __restrict__ o) {
  __shared__ float S[8][1024];     // 32 KB scores
  __shared__ float qs[8][DHEAD];   // 2 KB
  int t = threadIdx.x;
  int r0 = blockIdx.x * 8;
  int bh = blockIdx.y;
  int b = bh >> 4, hh = bh & 15;
  const float scale = 0.03125f;    // DIM^-0.5 = 1/32

  { // load+scale Q rows
    int e = t * 2, row = e >> 6, d = e & 63;
    const bf16* qp = q + ((size_t)(b * NN + r0 + row) * DIM) + hh * DHEAD + d;
    float2 f = __bfloat1622float2(*(const __hip_bfloat162*)qp);
    qs[row][d] = f.x * scale;
    qs[row][d + 1] = f.y * scale;
  }
  __syncthreads();

  // S = Q K^T
  for (int jt = 0; jt < 4; ++jt) {
    int j = jt * 256 + t;
    const bf16* kp = k + ((size_t)(b * MMK + j) * DIM) + hh * DHEAD;
    float kf[64];
    #pragma unroll
    for (int d2 = 0; d2 < 32; ++d2) {
      float2 f = __bfloat1622float2(*(const __hip_bfloat162*)(kp + 2 * d2));
      kf[2 * d2] = f.x; kf[2 * d2 + 1] = f.y;
    }
    #pragma unroll
    for (int r = 0; r < 8; ++r) {
      float s = 0.f;
      #pragma unroll
      for (int d = 0; d < 64; d += 4) {
        float4 qv = *(const float4*)(&qs[r][d]);   // broadcast read
        s += qv.x * kf[d] + qv.y * kf[d + 1] + qv.z * kf[d + 2] + qv.w * kf[d + 3];
      }
      S[r][j] = s;
    }
  }
  __syncthreads();

  // softmax per row: wave w -> rows 2w, 2w+1
  {
    int w = t >> 6, l = t & 63;
    #pragma unroll
    for (int ri = 0; ri < 2; ++ri) {
      int r = w * 2 + ri;
      float mx = -1e30f;
      for (int jj = l; jj < 1024; jj += 64) mx = fmaxf(mx, S[r][jj]);
      #pragma unroll
      for (int off = 32; off; off >>= 1) mx = fmaxf(mx, __shfl_xor(mx, off, 64));
      float sum = 0.f;
      for (int jj = l; jj < 1024; jj += 64) { float e = __expf(S[r][jj] - mx); S[r][jj] = e; sum += e; }
      #pragma unroll
      for (int off = 32; off; off >>= 1) sum += __shfl_xor(sum, off, 64);
      float inv = 1.0f / sum;
      for (int jj = l; jj < 1024; jj += 64) S[r][jj] *= inv;
    }
  }
  __syncthreads();

  // O = P V : thread -> (d = t&63, rows rg*2, rg*2+1 with rg = t>>6)
  {
    int d = t & 63, rg = t >> 6;
    float acc0 = 0.f, acc1 = 0.f;
    const bf16* vp = v + (size_t)(b * MMK) * DIM + hh * DHEAD + d;
    for (int j = 0; j < 1024; j += 4) {
      float4 p0 = *(const float4*)(&S[rg * 2][j]);      // broadcast
      float4 p1 = *(const float4*)(&S[rg * 2 + 1][j]);  // broadcast
      float v0 = __bfloat162float(vp[(size_t)(j + 0) * DIM]);
      float v1 = __bfloat162float(vp[(size_t)(j + 1) * DIM]);
      float v2 = __bfloat162float(vp[(size_t)(j + 2) * DIM]);
      float v3 = __bfloat162float(vp[(size_t)(j + 3) * DIM]);
      acc0 += p0.x * v0 + p0.y * v1 + p0.z * v2 + p0.w * v3;
      acc1 += p1.x * v0 + p1.y * v1 + p1.z * v2 + p1.w * v3;
    }
    size_t orow0 = (size_t)(b * NN + r0 + rg * 2) * DIM + hh * DHEAD + d;
    o[orow0] = __float2bfloat16(acc0);
    o[orow0 + DIM] = __float2bfloat16(acc1);
  }
}

// ---------------- host orchestration ----------------
extern "C" void kernel_launch(void* const* d_in, const int* in_sizes, int n_in,
                              void* d_out, int out_size, void* d_ws, size_t ws_size,
                              hipStream_t stream) {
  // ALL inputs are float32 per the reference file; output is float32.
  const float* x_in = (const float*)d_in[0];
  const float* m    = (const float*)d_in[1];
  const float* Wq   = (const float*)d_in[2];
  const float* Wk   = (const float*)d_in[3];
  const float* Wv   = (const float*)d_in[4];
  const float* Wo   = (const float*)d_in[5];
  const float* bo   = (const float*)d_in[6];
  const float* ln1w = (const float*)d_in[7];
  const float* ln1b = (const float*)d_in[8];
  const float* W1   = (const float*)d_in[9];
  const float* b1   = (const float*)d_in[10];
  const float* W2   = (const float*)d_in[11];
  const float* b2   = (const float*)d_in[12];
  const float* ln2w = (const float*)d_in[13];
  const float* ln2b = (const float*)d_in[14];

  // fp32 residual lives directly in d_out (4096x1024 f32 = 16 MB).
  float* xf = (float*)d_out;

  char* ws = (char*)d_ws;
  // workspace layout (44 MB):
  //   h    [ 0, 8) MB bf16  (LN out / attn out)
  //   mb   [ 8,16) MB bf16  (m converted once)
  //   qb   [16,24) MB bf16  -- reused as ffh low half in MLP phase
  //   kb   [24,32) MB bf16  -- reused as ffh high half in MLP phase
  //   vb   [32,40) MB bf16
  //   wt   [40,44) MB bf16  transposed-weight scratch (max 4MB)
  bf16* h   = (bf16*)(ws + 0);
  bf16* mb  = (bf16*)(ws + (8u  << 20));
  bf16* qb  = (bf16*)(ws + (16u << 20));
  bf16* kb  = (bf16*)(ws + (24u << 20));
  bf16* vb  = (bf16*)(ws + (32u << 20));
  bf16* ffh = (bf16*)(ws + (16u << 20));   // 4096x2048 bf16 = 16MB
  bf16* wt  = (bf16*)(ws + (40u << 20));

  const int NTOK = ROWS * DIM;   // 4M elements

  // init residual = x (f32, 16MB) and convert m to bf16
  hipMemcpyAsync(xf, x_in, (size_t)NTOK * sizeof(float), hipMemcpyDeviceToDevice, stream);
  f2b_kernel<<<dim3((NTOK + 255) / 256), dim3(256), 0, stream>>>(m, mb, NTOK);

  dim3 blk(256);
  dim3 tblk(32, 8);
  dim3 gemm_n1(DIM / 64, ROWS / 64);     // N=1024
  dim3 gemm_n2(2048 / 64, ROWS / 64);    // N=2048 (MLP half)
  dim3 tr_1k(DIM / 32, DIM / 32);        // 1024x1024 weight
  dim3 tr_w1(2048 / 32, DIM / 32);       // W1 half
  dim3 tr_w2(DIM / 32, 2048 / 32);       // W2 half
  dim3 attn_grid(NN / 8, BB * HEADS);

  for (int L = 0; L < DEPTH; ++L) {
    const float* WqL = Wq + (size_t)L * DIM * DIM;
    const float* WkL = Wk + (size_t)L * DIM * DIM;
    const float* WvL = Wv + (size_t)L * DIM * DIM;
    const float* WoL = Wo + (size_t)L * DIM * DIM;
    const float* W1L = W1 + (size_t)L * DIM * MLPD;
    const float* W2L = W2 + (size_t)L * MLPD * DIM;

    // --- cross-attention block ---
    ln_kernel<<<dim3(ROWS), blk, 0, stream>>>(xf, ln1w + L * DIM, ln1b + L * DIM, h);

    transpose_f2b<<<tr_1k, tblk, 0, stream>>>(WqL, wt, DIM, 0, 0, DIM);
    gemm_kernel<<<gemm_n1, blk, 0, stream>>>(h, wt, nullptr, qb, nullptr, DIM, DIM, MODE_PLAIN);
    transpose_f2b<<<tr_1k, tblk, 0, stream>>>(WkL, wt, DIM, 0, 0, DIM);
    gemm_kernel<<<gemm_n1, blk, 0, stream>>>(mb, wt, nullptr, kb, nullptr, DIM, DIM, MODE_PLAIN);
    transpose_f2b<<<tr_1k, tblk, 0, stream>>>(WvL, wt, DIM, 0, 0, DIM);
    gemm_kernel<<<gemm_n1, blk, 0, stream>>>(mb, wt, nullptr, vb, nullptr, DIM, DIM, MODE_PLAIN);

    attn_kernel<<<attn_grid, blk, 0, stream>>>(qb, kb, vb, h);

    transpose_f2b<<<tr_1k, tblk, 0, stream>>>(WoL, wt, DIM, 0, 0, DIM);
    gemm_kernel<<<gemm_n1, blk, 0, stream>>>(h, wt, bo + L * DIM, nullptr, xf, DIM, DIM, MODE_RES);

    // --- MLP block (two N=2048 halves; ffh reuses qb/kb space) ---
    ln_kernel<<<dim3(ROWS), blk, 0, stream>>>(xf, ln2w + L * DIM, ln2b + L * DIM, h);

    for (int half = 0; half < 2; ++half) {
      transpose_f2b<<<tr_w1, tblk, 0, stream>>>(W1L, wt, MLPD, 0, half * 2048, DIM);
      gemm_kernel<<<gemm_n2, blk, 0, stream>>>(h, wt, b1 + (size_t)L * MLPD + half * 2048, ffh, nullptr,
                                               2048, DIM, MODE_GELU);
      transpose_f2b<<<tr_w2, tblk, 0, stream>>>(W2L, wt, DIM, half * 2048, 0, 2048);
      gemm_kernel<<<gemm_n1, blk, 0, stream>>>(ffh, wt, (half == 0) ? (b2 + (size_t)L * DIM) : nullptr,
                                               nullptr, xf, DIM, 2048, MODE_RES);
    }
  }
  // residual already accumulated in d_out (f32) — no final copy needed.
}

// Round 4
// 1818.564 us; speedup vs baseline: 4.1211x; 4.1211x over previous
//
#include <hip/hip_runtime.h>
#include <hip/hip_bf16.h>
#include <math.h>

typedef __hip_bfloat16 bf16;
typedef __attribute__((ext_vector_type(8))) short bf16x8;
typedef __attribute__((ext_vector_type(4))) float f32x4;

#define DEPTH  4
#define HEADS  16
#define DIM    1024
#define DHEAD  64
#define MLPD   4096
#define BB     4
#define NN     1024
#define MMK    1024
#define ROWS   (BB*NN)     // 4096 token rows

__device__ inline float bitsbf(short s) {
  union { float f; unsigned u; } c; c.u = ((unsigned)(unsigned short)s) << 16; return c.f;
}
__device__ inline short bfbits(float f) {
  bf16 h = __float2bfloat16(f); return *(short*)&h;
}

// ---------------- f32 -> bf16 convert ----------------
__global__ __launch_bounds__(256) void f2b_kernel(const float* __restrict__ in, bf16* __restrict__ out, int n) {
  int i = blockIdx.x * 256 + threadIdx.x;
  if (i < n) out[i] = __float2bfloat16(in[i]);
}

// ---------------- generalized transpose + f32->bf16 ----------------
// out[n][k] = bf16( in[(rowOff + k) * inStride + colOff + n] )
__global__ __launch_bounds__(256) void transpose_f2b(const float* __restrict__ in, bf16* __restrict__ out,
                                                     int inStride, int rowOff, int colOff, int outStride) {
  __shared__ float tile[32][33];
  int n0 = blockIdx.x * 32, k0 = blockIdx.y * 32;
  int tx = threadIdx.x, ty = threadIdx.y;          // 32 x 8
  #pragma unroll
  for (int i = 0; i < 32; i += 8)
    tile[ty + i][tx] = in[(size_t)(rowOff + k0 + ty + i) * inStride + colOff + n0 + tx];
  __syncthreads();
  #pragma unroll
  for (int i = 0; i < 32; i += 8)
    out[(size_t)(n0 + ty + i) * outStride + k0 + tx] = __float2bfloat16(tile[tx][ty + i]);
}

// ---------------- layernorm: f32 in -> bf16 out ----------------
__global__ __launch_bounds__(256) void ln_kernel(const float* __restrict__ x, const float* __restrict__ w,
                                                 const float* __restrict__ b, bf16* __restrict__ out) {
  int row = blockIdx.x, t = threadIdx.x;
  const float* xr = x + (size_t)row * DIM;
  float4 xv = *(const float4*)(xr + t * 4);
  float s  = xv.x + xv.y + xv.z + xv.w;
  float s2 = xv.x * xv.x + xv.y * xv.y + xv.z * xv.z + xv.w * xv.w;
  #pragma unroll
  for (int off = 32; off; off >>= 1) { s += __shfl_xor(s, off, 64); s2 += __shfl_xor(s2, off, 64); }
  __shared__ float sh_s[4], sh_s2[4], sh_mu, sh_rstd;
  int wid = t >> 6;
  if ((t & 63) == 0) { sh_s[wid] = s; sh_s2[wid] = s2; }
  __syncthreads();
  if (t == 0) {
    float S1 = sh_s[0] + sh_s[1] + sh_s[2] + sh_s[3];
    float S2 = sh_s2[0] + sh_s2[1] + sh_s2[2] + sh_s2[3];
    float mu = S1 * (1.0f / DIM);
    float var = S2 * (1.0f / DIM) - mu * mu;
    sh_mu = mu; sh_rstd = rsqrtf(var + 1e-5f);
  }
  __syncthreads();
  float mu = sh_mu, rstd = sh_rstd;
  float4 wv = *(const float4*)(w + t * 4);
  float4 bv = *(const float4*)(b + t * 4);
  bf16* orow = out + (size_t)row * DIM + t * 4;
  orow[0] = __float2bfloat16((xv.x - mu) * rstd * wv.x + bv.x);
  orow[1] = __float2bfloat16((xv.y - mu) * rstd * wv.y + bv.y);
  orow[2] = __float2bfloat16((xv.z - mu) * rstd * wv.z + bv.z);
  orow[3] = __float2bfloat16((xv.w - mu) * rstd * wv.w + bv.w);
}

// ---------------- GEMM: C = A(M,K) x Bt(N,K)^T ----------------
#define MODE_PLAIN 0
#define MODE_GELU  1
#define MODE_RES   2
#define LDK 40

__global__ __launch_bounds__(256) void gemm_kernel(const bf16* __restrict__ A, const bf16* __restrict__ Bt,
                                                   const float* __restrict__ bias, bf16* __restrict__ outb,
                                                   float* __restrict__ resf, int N, int K, int mode) {
  __shared__ bf16 As[64][LDK];
  __shared__ bf16 Bs[64][LDK];
  int t = threadIdx.x;
  int col0 = blockIdx.x * 64, row0 = blockIdx.y * 64;
  int lane = t & 63, wid = t >> 6;
  int wm = (wid >> 1) * 32, wn = (wid & 1) * 32;
  int l15 = lane & 15, quad = lane >> 4;
  int am = t >> 2, ak = (t & 3) * 8;

  f32x4 acc00 = {}, acc01 = {}, acc10 = {}, acc11 = {};

  const bf16* aptr = A  + (size_t)(row0 + am) * K + ak;
  const bf16* bptr = Bt + (size_t)(col0 + am) * K + ak;

  for (int k0 = 0; k0 < K; k0 += 32) {
    *(bf16x8*)(&As[am][ak]) = *(const bf16x8*)(aptr + k0);
    *(bf16x8*)(&Bs[am][ak]) = *(const bf16x8*)(bptr + k0);
    __syncthreads();
    bf16x8 a0 = *(const bf16x8*)(&As[wm + l15][quad * 8]);
    bf16x8 a1 = *(const bf16x8*)(&As[wm + 16 + l15][quad * 8]);
    bf16x8 b0 = *(const bf16x8*)(&Bs[wn + l15][quad * 8]);
    bf16x8 b1 = *(const bf16x8*)(&Bs[wn + 16 + l15][quad * 8]);
    acc00 = __builtin_amdgcn_mfma_f32_16x16x32_bf16(a0, b0, acc00, 0, 0, 0);
    acc01 = __builtin_amdgcn_mfma_f32_16x16x32_bf16(a0, b1, acc01, 0, 0, 0);
    acc10 = __builtin_amdgcn_mfma_f32_16x16x32_bf16(a1, b0, acc10, 0, 0, 0);
    acc11 = __builtin_amdgcn_mfma_f32_16x16x32_bf16(a1, b1, acc11, 0, 0, 0);
    __syncthreads();
  }

  f32x4 accs[2][2] = {{acc00, acc01}, {acc10, acc11}};
  #pragma unroll
  for (int i = 0; i < 2; ++i) {
    #pragma unroll
    for (int j = 0; j < 2; ++j) {
      int gcol = col0 + wn + j * 16 + l15;
      float bval = (mode != MODE_PLAIN && bias != nullptr) ? bias[gcol] : 0.0f;
      #pragma unroll
      for (int r = 0; r < 4; ++r) {
        int grow = row0 + wm + i * 16 + quad * 4 + r;
        float val = accs[i][j][r];
        size_t idx = (size_t)grow * N + gcol;
        if (mode == MODE_RES) {
          resf[idx] = resf[idx] + val + bval;
        } else {
          if (mode == MODE_GELU) {
            float u = val + bval;
            val = 0.5f * u * (1.0f + erff(u * 0.70710678118654752f));
          }
          outb[idx] = __float2bfloat16(val);
        }
      }
    }
  }
}

// ---------------- MFMA flash attention ----------------
// Block: 64 Q-rows of one (b,h). 4 waves, wave w owns Q rows [w*16, w*16+16).
// Iterate M in K/V-tiles of 64 with online softmax.
#define ALDP 72   // LDS leading dim (elements); 144B row stride, 16B aligned

__global__ __launch_bounds__(256) void attn_mfma_kernel(const bf16* __restrict__ q, const bf16* __restrict__ k,
                                                        const bf16* __restrict__ v, bf16* __restrict__ o) {
  __shared__ __align__(16) short Kl[64][ALDP];   // K tile [kv][d]
  __shared__ __align__(16) short Vt[64][ALDP];   // V tile transposed [d][kv]
  __shared__ __align__(16) short Pl[64][ALDP];   // P tile [qrow][kv] (bf16)

  int t = threadIdx.x;
  int lane = t & 63, w = t >> 6;
  int l15 = lane & 15, quad = lane >> 4;
  int qt = blockIdx.x;                  // q tile
  int bh = blockIdx.y;
  int b = bh >> 4, hh = bh & 15;

  // Q fragments (A-operand layout), pre-scaled by 1/32 (power of 2: exact in bf16)
  bf16x8 qfrag[2];
  {
    const bf16* qp = q + (size_t)(b * NN + qt * 64 + w * 16 + l15) * DIM + hh * DHEAD + quad * 8;
    #pragma unroll
    for (int ks = 0; ks < 2; ++ks) {
      bf16x8 raw = *(const bf16x8*)(qp + ks * 32);
      bf16x8 sc;
      #pragma unroll
      for (int e = 0; e < 8; ++e) sc[e] = bfbits(bitsbf(raw[e]) * 0.03125f);
      qfrag[ks] = sc;
    }
  }

  f32x4 Oacc[4] = {{}, {}, {}, {}};
  float mrow[4] = {-1e30f, -1e30f, -1e30f, -1e30f};
  float lrow[4] = {0.f, 0.f, 0.f, 0.f};

  int srow = t >> 2, sc0 = (t & 3) * 16;   // staging coords

  for (int kt = 0; kt < MMK / 64; ++kt) {
    __syncthreads();   // previous iteration's PV reads done
    { // stage K tile and V^T tile
      const bf16* kp = k + (size_t)(b * MMK + kt * 64 + srow) * DIM + hh * DHEAD + sc0;
      *(bf16x8*)&Kl[srow][sc0]     = *(const bf16x8*)kp;
      *(bf16x8*)&Kl[srow][sc0 + 8] = *(const bf16x8*)(kp + 8);
      const bf16* vp = v + (size_t)(b * MMK + kt * 64 + srow) * DIM + hh * DHEAD + sc0;
      bf16x8 v0 = *(const bf16x8*)vp;
      bf16x8 v1 = *(const bf16x8*)(vp + 8);
      #pragma unroll
      for (int e = 0; e < 8; ++e) {
        Vt[sc0 + e][srow]     = v0[e];
        Vt[sc0 + 8 + e][srow] = v1[e];
      }
    }
    __syncthreads();

    // S = Q K^T  (C-layout: row w*16+quad*4+r, col j*16+l15)
    f32x4 S[4] = {{}, {}, {}, {}};
    #pragma unroll
    for (int ks = 0; ks < 2; ++ks) {
      #pragma unroll
      for (int j = 0; j < 4; ++j) {
        bf16x8 bfr = *(const bf16x8*)&Kl[j * 16 + l15][ks * 32 + quad * 8];
        S[j] = __builtin_amdgcn_mfma_f32_16x16x32_bf16(qfrag[ks], bfr, S[j], 0, 0, 0);
      }
    }

    // online softmax + write P (bf16) to LDS
    #pragma unroll
    for (int r = 0; r < 4; ++r) {
      float tm = fmaxf(fmaxf(S[0][r], S[1][r]), fmaxf(S[2][r], S[3][r]));
      tm = fmaxf(tm, __shfl_xor(tm, 1, 64));
      tm = fmaxf(tm, __shfl_xor(tm, 2, 64));
      tm = fmaxf(tm, __shfl_xor(tm, 4, 64));
      tm = fmaxf(tm, __shfl_xor(tm, 8, 64));
      float mn = fmaxf(mrow[r], tm);
      float alpha = __expf(mrow[r] - mn);
      mrow[r] = mn;
      float rs = 0.f;
      #pragma unroll
      for (int j = 0; j < 4; ++j) {
        float p = __expf(S[j][r] - mn);
        S[j][r] = p;
        rs += p;
      }
      rs += __shfl_xor(rs, 1, 64);
      rs += __shfl_xor(rs, 2, 64);
      rs += __shfl_xor(rs, 4, 64);
      rs += __shfl_xor(rs, 8, 64);
      lrow[r] = lrow[r] * alpha + rs;
      #pragma unroll
      for (int j = 0; j < 4; ++j) {
        Oacc[j][r] *= alpha;
        Pl[w * 16 + quad * 4 + r][j * 16 + l15] = bfbits(S[j][r]);
      }
    }
    __syncthreads();

    // O += P V   (A = P rows w*16+l15, B = Vt[n=d][k=kv])
    #pragma unroll
    for (int ks = 0; ks < 2; ++ks) {
      bf16x8 pa = *(const bf16x8*)&Pl[w * 16 + l15][ks * 32 + quad * 8];
      #pragma unroll
      for (int j = 0; j < 4; ++j) {
        bf16x8 vb = *(const bf16x8*)&Vt[j * 16 + l15][ks * 32 + quad * 8];
        Oacc[j] = __builtin_amdgcn_mfma_f32_16x16x32_bf16(pa, vb, Oacc[j], 0, 0, 0);
      }
    }
  }

  // epilogue: O /= l, write bf16
  #pragma unroll
  for (int r = 0; r < 4; ++r) {
    float inv = 1.0f / lrow[r];
    bf16* op = o + (size_t)(b * NN + qt * 64 + w * 16 + quad * 4 + r) * DIM + hh * DHEAD;
    #pragma unroll
    for (int j = 0; j < 4; ++j)
      op[j * 16 + l15] = __float2bfloat16(Oacc[j][r] * inv);
  }
}

// ---------------- host orchestration ----------------
extern "C" void kernel_launch(void* const* d_in, const int* in_sizes, int n_in,
                              void* d_out, int out_size, void* d_ws, size_t ws_size,
                              hipStream_t stream) {
  const float* x_in = (const float*)d_in[0];
  const float* m    = (const float*)d_in[1];
  const float* Wq   = (const float*)d_in[2];
  const float* Wk   = (const float*)d_in[3];
  const float* Wv   = (const float*)d_in[4];
  const float* Wo   = (const float*)d_in[5];
  const float* bo   = (const float*)d_in[6];
  const float* ln1w = (const float*)d_in[7];
  const float* ln1b = (const float*)d_in[8];
  const float* W1   = (const float*)d_in[9];
  const float* b1   = (const float*)d_in[10];
  const float* W2   = (const float*)d_in[11];
  const float* b2   = (const float*)d_in[12];
  const float* ln2w = (const float*)d_in[13];
  const float* ln2b = (const float*)d_in[14];

  float* xf = (float*)d_out;   // fp32 residual in d_out

  char* ws = (char*)d_ws;
  bf16* h   = (bf16*)(ws + 0);
  bf16* mb  = (bf16*)(ws + (8u  << 20));
  bf16* qb  = (bf16*)(ws + (16u << 20));
  bf16* kb  = (bf16*)(ws + (24u << 20));
  bf16* vb  = (bf16*)(ws + (32u << 20));
  bf16* ffh = (bf16*)(ws + (16u << 20));
  bf16* wt  = (bf16*)(ws + (40u << 20));

  const int NTOK = ROWS * DIM;

  hipMemcpyAsync(xf, x_in, (size_t)NTOK * sizeof(float), hipMemcpyDeviceToDevice, stream);
  f2b_kernel<<<dim3((NTOK + 255) / 256), dim3(256), 0, stream>>>(m, mb, NTOK);

  dim3 blk(256);
  dim3 tblk(32, 8);
  dim3 gemm_n1(DIM / 64, ROWS / 64);
  dim3 gemm_n2(2048 / 64, ROWS / 64);
  dim3 tr_1k(DIM / 32, DIM / 32);
  dim3 tr_w1(2048 / 32, DIM / 32);
  dim3 tr_w2(DIM / 32, 2048 / 32);
  dim3 attn_grid(NN / 64, BB * HEADS);

  for (int L = 0; L < DEPTH; ++L) {
    const float* WqL = Wq + (size_t)L * DIM * DIM;
    const float* WkL = Wk + (size_t)L * DIM * DIM;
    const float* WvL = Wv + (size_t)L * DIM * DIM;
    const float* WoL = Wo + (size_t)L * DIM * DIM;
    const float* W1L = W1 + (size_t)L * DIM * MLPD;
    const float* W2L = W2 + (size_t)L * MLPD * DIM;

    // --- cross-attention block ---
    ln_kernel<<<dim3(ROWS), blk, 0, stream>>>(xf, ln1w + L * DIM, ln1b + L * DIM, h);

    transpose_f2b<<<tr_1k, tblk, 0, stream>>>(WqL, wt, DIM, 0, 0, DIM);
    gemm_kernel<<<gemm_n1, blk, 0, stream>>>(h, wt, nullptr, qb, nullptr, DIM, DIM, MODE_PLAIN);
    transpose_f2b<<<tr_1k, tblk, 0, stream>>>(WkL, wt, DIM, 0, 0, DIM);
    gemm_kernel<<<gemm_n1, blk, 0, stream>>>(mb, wt, nullptr, kb, nullptr, DIM, DIM, MODE_PLAIN);
    transpose_f2b<<<tr_1k, tblk, 0, stream>>>(WvL, wt, DIM, 0, 0, DIM);
    gemm_kernel<<<gemm_n1, blk, 0, stream>>>(mb, wt, nullptr, vb, nullptr, DIM, DIM, MODE_PLAIN);

    attn_mfma_kernel<<<attn_grid, blk, 0, stream>>>(qb, kb, vb, h);

    transpose_f2b<<<tr_1k, tblk, 0, stream>>>(WoL, wt, DIM, 0, 0, DIM);
    gemm_kernel<<<gemm_n1, blk, 0, stream>>>(h, wt, bo + L * DIM, nullptr, xf, DIM, DIM, MODE_RES);

    // --- MLP block ---
    ln_kernel<<<dim3(ROWS), blk, 0, stream>>>(xf, ln2w + L * DIM, ln2b + L * DIM, h);

    for (int half = 0; half < 2; ++half) {
      transpose_f2b<<<tr_w1, tblk, 0, stream>>>(W1L, wt, MLPD, 0, half * 2048, DIM);
      gemm_kernel<<<gemm_n2, blk, 0, stream>>>(h, wt, b1 + (size_t)L * MLPD + half * 2048, ffh, nullptr,
                                               2048, DIM, MODE_GELU);
      transpose_f2b<<<tr_w2, tblk, 0, stream>>>(W2L, wt, DIM, half * 2048, 0, 2048);
      gemm_kernel<<<gemm_n1, blk, 0, stream>>>(ffh, wt, (half == 0) ? (b2 + (size_t)L * DIM) : nullptr,
                                               nullptr, xf, DIM, 2048, MODE_RES);
    }
  }
}